// Round 1
// baseline (82.679 us; speedup 1.0000x reference)
//
#include <hip/hip_runtime.h>
#include <stdint.h>

#define N_NODES 3072
#define NPOS 13
#define LL 4096
#define LWORDS 64   // uint64 words per 4096-bit mask row

// ---------------- K1: lane codes + packed feature bits ----------------
__global__ __launch_bounds__(256) void k1_lanes(const float* __restrict__ nf,
                                                int* __restrict__ lane,
                                                unsigned int* __restrict__ packed) {
    int i = blockIdx.x * blockDim.x + threadIdx.x;
    if (i >= N_NODES) return;
    const float* b = nf + i * NPOS;
    unsigned int p = 0;
    int ln = 0;
#pragma unroll
    for (int k = 0; k < NPOS; ++k) {
        float v = b[k];
        int bit = (int)v;            // values are exactly 0.0 / 1.0
        if (bit) p |= (1u << k);
        if (k < NPOS - 1) ln = ln * 2 + bit;   // MSB-first, first 12 bits
    }
    bool valid = (b[0] >= 0.0f);
    if (valid) p |= 0x80000000u;
    lane[i] = valid ? ln : 0;
    packed[i] = p;
}

// ---------------- K2: sign bitmask S[a][w], bit k = topo[a][64w+k] >= 0 ----------------
__global__ __launch_bounds__(256) void k2_signmask(const float* __restrict__ topo,
                                                   unsigned long long* __restrict__ S) {
    int gid = blockIdx.x * blockDim.x + threadIdx.x;   // one element per thread
    float v = topo[gid];
    unsigned long long m = __ballot(v >= 0.0f);
    if ((threadIdx.x & 63) == 0) S[gid >> 6] = m;
}

// ---------------- K2b: 64x64 bit-transpose S -> T, T[b][w] bit k = topo[64w+k][b] >= 0 ----------------
__device__ inline unsigned long long shflx64(unsigned long long v, int lanemask) {
    unsigned int lo = (unsigned int)v, hi = (unsigned int)(v >> 32);
    lo = (unsigned int)__shfl_xor((int)lo, lanemask);
    hi = (unsigned int)__shfl_xor((int)hi, lanemask);
    return ((unsigned long long)hi << 32) | lo;
}

__global__ __launch_bounds__(256) void k2b_transpose(const unsigned long long* __restrict__ S,
                                                     unsigned long long* __restrict__ T) {
    int wave = (blockIdx.x * blockDim.x + threadIdx.x) >> 6;  // tile id
    int l = threadIdx.x & 63;
    int tA = wave >> 6;      // row-tile (a)
    int tB = wave & 63;      // col-tile (b)
    unsigned long long x = S[(tA * 64 + l) * LWORDS + tB];
#pragma unroll
    for (int j = 32; j >= 1; j >>= 1) {
        unsigned long long m;
        switch (j) {
            case 32: m = 0x00000000FFFFFFFFULL; break;
            case 16: m = 0x0000FFFF0000FFFFULL; break;
            case 8:  m = 0x00FF00FF00FF00FFULL; break;
            case 4:  m = 0x0F0F0F0F0F0F0F0FULL; break;
            case 2:  m = 0x3333333333333333ULL; break;
            default: m = 0x5555555555555555ULL; break;
        }
        unsigned long long t = shflx64(x, j);
        if ((l & j) == 0) x = (x & m)  | ((t << j) & ~m);
        else              x = (x & ~m) | ((t >> j) & m);
    }
    T[(tB * 64 + l) * LWORDS + tA] = x;
}

// ---------------- K3: column degree -> dinv[i] = 1/sqrt(deg) ----------------
__global__ __launch_bounds__(256) void k3_deg(const unsigned long long* __restrict__ T,
                                              const int* __restrict__ lane,
                                              const unsigned int* __restrict__ packed,
                                              float* __restrict__ dinv) {
    int i = blockIdx.x;
    __shared__ unsigned long long row[LWORDS];
    __shared__ int red[4];
    int tid = threadIdx.x;
    int li = lane[i];
    unsigned int vi = packed[i] >> 31;
    if (tid < LWORDS) row[tid] = T[li * LWORDS + tid];
    __syncthreads();
    int cnt = 0;
    for (int j = tid; j < N_NODES; j += 256) {
        int lj = lane[j];
        unsigned int vj = packed[j] >> 31;
        unsigned int bit = (unsigned int)(row[lj >> 6] >> (lj & 63)) & 1u;
        cnt += (int)((j == i) | (vi & vj & bit));
    }
#pragma unroll
    for (int off = 32; off; off >>= 1) cnt += __shfl_down(cnt, off);
    if ((tid & 63) == 0) red[tid >> 6] = cnt;
    __syncthreads();
    if (tid == 0) {
        int d = red[0] + red[1] + red[2] + red[3];
        dinv[i] = (d > 0) ? (1.0f / sqrtf((float)d)) : 0.0f;
    }
}

// ---------------- K4: agg[i][f] = dinv[i] * sum_j adj[j,i]*dinv[j]*bit_f(j) ----------------
__global__ __launch_bounds__(256) void k4_agg(const unsigned long long* __restrict__ T,
                                              const int* __restrict__ lane,
                                              const unsigned int* __restrict__ packed,
                                              const float* __restrict__ dinv,
                                              float* __restrict__ agg) {
    int i = blockIdx.x;
    __shared__ unsigned long long row[LWORDS];
    __shared__ float red[4][NPOS];
    int tid = threadIdx.x;
    int li = lane[i];
    unsigned int vi = packed[i] >> 31;
    if (tid < LWORDS) row[tid] = T[li * LWORDS + tid];
    __syncthreads();
    float acc[NPOS];
#pragma unroll
    for (int f = 0; f < NPOS; ++f) acc[f] = 0.0f;
    for (int j = tid; j < N_NODES; j += 256) {
        int lj = lane[j];
        unsigned int pj = packed[j];
        unsigned int vj = pj >> 31;
        unsigned int bit = (unsigned int)(row[lj >> 6] >> (lj & 63)) & 1u;
        bool adj = (j == i) | (vi & vj & bit);
        float w = adj ? dinv[j] : 0.0f;
#pragma unroll
        for (int f = 0; f < NPOS; ++f)
            acc[f] += ((pj >> f) & 1u) ? w : 0.0f;
    }
    int l = tid & 63, wv = tid >> 6;
#pragma unroll
    for (int f = 0; f < NPOS; ++f) {
        float v = acc[f];
#pragma unroll
        for (int off = 32; off; off >>= 1) v += __shfl_down(v, off);
        if (l == 0) red[wv][f] = v;
    }
    __syncthreads();
    if (tid < NPOS) {
        float di = dinv[i];
        agg[i * NPOS + tid] = di * (red[0][tid] + red[1][tid] + red[2][tid] + red[3][tid]);
    }
}

// ---------------- K5: out[i][n] = bias[n] + sum_f agg[i][f] * W[n][f] ----------------
#define NT 512
#define IT 16
__global__ __launch_bounds__(256) void k5_out(const float* __restrict__ agg,
                                              const float* __restrict__ W,
                                              const float* __restrict__ bias,
                                              float* __restrict__ out) {
    __shared__ float Wt[NT * NPOS];
    __shared__ float bt[NT];
    __shared__ float at[IT * NPOS];
    int tid = threadIdx.x;
    int n0 = blockIdx.x * NT;
    int i0 = blockIdx.y * IT;
    for (int idx = tid; idx < NT * NPOS; idx += 256) Wt[idx] = W[n0 * NPOS + idx];
    for (int idx = tid; idx < NT; idx += 256) bt[idx] = bias[n0 + idx];
    for (int idx = tid; idx < IT * NPOS; idx += 256) at[idx] = agg[i0 * NPOS + idx];
    __syncthreads();

    int n4 = (tid & 127) << 2;      // 0..508
    int ib = (tid >> 7) * 8;        // 0 or 8

    float wr[NPOS][4];
#pragma unroll
    for (int f = 0; f < NPOS; ++f)
#pragma unroll
        for (int r = 0; r < 4; ++r)
            wr[f][r] = Wt[(n4 + r) * NPOS + f];
    float b0 = bt[n4], b1 = bt[n4 + 1], b2 = bt[n4 + 2], b3 = bt[n4 + 3];

#pragma unroll
    for (int q = 0; q < 8; ++q) {
        int il = ib + q;
        float a0 = b0, a1 = b1, a2 = b2, a3 = b3;
#pragma unroll
        for (int f = 0; f < NPOS; ++f) {
            float av = at[il * NPOS + f];
            a0 += av * wr[f][0];
            a1 += av * wr[f][1];
            a2 += av * wr[f][2];
            a3 += av * wr[f][3];
        }
        float4 o = make_float4(a0, a1, a2, a3);
        *(float4*)&out[(size_t)(i0 + il) * N_NODES + n0 + n4] = o;
    }
}

extern "C" void kernel_launch(void* const* d_in, const int* in_sizes, int n_in,
                              void* d_out, int out_size, void* d_ws, size_t ws_size,
                              hipStream_t stream) {
    const float* nf   = (const float*)d_in[0];   // node_feature [1,3072,13]
    const float* topo = (const float*)d_in[1];   // topo [1,1,4096,4096]
    const float* W    = (const float*)d_in[2];   // gcn_weight [3072,13]
    const float* bias = (const float*)d_in[3];   // gcn_bias [3072]
    float* out = (float*)d_out;

    // small scratch in ws (~200 KB)
    char* ws = (char*)d_ws;
    int*          lane   = (int*)ws;                          // 12 KB
    unsigned int* packed = (unsigned int*)(ws + 12288);       // 12 KB
    float*        dinv   = (float*)(ws + 24576);              // 12 KB
    float*        agg    = (float*)(ws + 36864);              // 160 KB

    // transient 2 MB masks live in d_out; fully overwritten by k5 at the end
    unsigned long long* S = (unsigned long long*)d_out;       // [4096][64]
    unsigned long long* T = S + (size_t)LL * LWORDS;          // [4096][64]

    k1_lanes<<<(N_NODES + 255) / 256, 256, 0, stream>>>(nf, lane, packed);
    k2_signmask<<<(LL * LL) / 256, 256, 0, stream>>>(topo, S);
    k2b_transpose<<<(LL / 64) * (LL / 64) * 64 / 256, 256, 0, stream>>>(S, T);
    k3_deg<<<N_NODES, 256, 0, stream>>>(T, lane, packed, dinv);
    k4_agg<<<N_NODES, 256, 0, stream>>>(T, lane, packed, dinv, agg);
    dim3 g5(N_NODES / NT, N_NODES / IT);
    k5_out<<<g5, 256, 0, stream>>>(agg, W, bias, out);
}

// Round 2
// 69.043 us; speedup vs baseline: 1.1975x; 1.1975x over previous
//
#include <hip/hip_runtime.h>
#include <stdint.h>

#define N_NODES 3072
#define NPOS 13
#define LL 4096
#define LWORDS 64   // uint64 words per 4096-bit mask row

// ---------------- KA: fused sign-mask + bit-transpose (+ lane codes in last block) ----
// Blocks 0..4095: each handles a 64x64 tile of topo. Reads coalesced (float4),
// stages in padded LDS, ballots COLUMNS -> writes T directly:
//   T[c][w] bit k  =  (topo[64w+k][c] >= 0)
// Block 4096: computes lane codes + packed feature bits for all 3072 nodes.
__global__ __launch_bounds__(256) void kA_mask_lanes(const float* __restrict__ topo,
                                                     const float* __restrict__ nf,
                                                     unsigned long long* __restrict__ T,
                                                     int* __restrict__ lane,
                                                     unsigned int* __restrict__ packed) {
    int bid = blockIdx.x;
    int tid = threadIdx.x;

    if (bid >= LL * LL / (64 * 64)) {
        // ---- lane-code block ----
        for (int i = tid; i < N_NODES; i += 256) {
            const float* b = nf + i * NPOS;
            unsigned int p = 0;
            int ln = 0;
#pragma unroll
            for (int k = 0; k < NPOS; ++k) {
                int bit = (int)b[k];             // exactly 0.0 / 1.0
                if (bit) p |= (1u << k);
                if (k < NPOS - 1) ln = ln * 2 + bit;  // MSB-first, first 12 bits
            }
            bool valid = (b[0] >= 0.0f);
            if (valid) p |= 0x80000000u;
            lane[i] = valid ? ln : 0;
            packed[i] = p;
        }
        return;
    }

    int tA = bid & 63;   // row tile
    int tB = bid >> 6;   // col tile
    __shared__ float tile[64 * 65];   // pad 65: col-read banks (l+col)%32 conflict-free

    const float* src = topo + (size_t)(tA * 64) * LL + tB * 64;
#pragma unroll
    for (int p = 0; p < 4; ++p) {
        int q = p * 1024 + tid * 4;       // linear float index in 64x64 tile
        int r = q >> 6, c = q & 63;
        float4 v = *(const float4*)&src[(size_t)r * LL + c];
        float* d = &tile[r * 65 + c];     // scalar stores (65-pad: float4 would misalign)
        d[0] = v.x; d[1] = v.y; d[2] = v.z; d[3] = v.w;
    }
    __syncthreads();

    int w = tid >> 6, l = tid & 63;
#pragma unroll
    for (int cc = 0; cc < 16; ++cc) {
        int col = w * 16 + cc;
        unsigned long long m = __ballot(tile[l * 65 + col] >= 0.0f);
        if (l == 0) T[(size_t)(tB * 64 + col) * LWORDS + tA] = m;
    }
}

// ---------------- K3: column degree -> dinv[i] = 1/sqrt(deg) ----------------
__global__ __launch_bounds__(256) void k3_deg(const unsigned long long* __restrict__ T,
                                              const int* __restrict__ lane,
                                              const unsigned int* __restrict__ packed,
                                              float* __restrict__ dinv) {
    int i = blockIdx.x;
    __shared__ unsigned long long row[LWORDS];
    __shared__ int red[4];
    int tid = threadIdx.x;
    int li = lane[i];
    unsigned int vi = packed[i] >> 31;
    if (tid < LWORDS) row[tid] = T[(size_t)li * LWORDS + tid];
    __syncthreads();
    int cnt = 0;
    for (int j = tid; j < N_NODES; j += 256) {
        int lj = lane[j];
        unsigned int vj = packed[j] >> 31;
        unsigned int bit = (unsigned int)(row[lj >> 6] >> (lj & 63)) & 1u;
        cnt += (int)((j == i) | (vi & vj & bit));
    }
#pragma unroll
    for (int off = 32; off; off >>= 1) cnt += __shfl_down(cnt, off);
    if ((tid & 63) == 0) red[tid >> 6] = cnt;
    __syncthreads();
    if (tid == 0) {
        int d = red[0] + red[1] + red[2] + red[3];
        dinv[i] = (d > 0) ? (1.0f / sqrtf((float)d)) : 0.0f;
    }
}

// ---------------- K4: agg[i][f] = dinv[i] * sum_j adj[j,i]*dinv[j]*bit_f(j) ----------------
__global__ __launch_bounds__(256) void k4_agg(const unsigned long long* __restrict__ T,
                                              const int* __restrict__ lane,
                                              const unsigned int* __restrict__ packed,
                                              const float* __restrict__ dinv,
                                              float* __restrict__ agg) {
    int i = blockIdx.x;
    __shared__ unsigned long long row[LWORDS];
    __shared__ float red[4][NPOS];
    int tid = threadIdx.x;
    int li = lane[i];
    unsigned int vi = packed[i] >> 31;
    if (tid < LWORDS) row[tid] = T[(size_t)li * LWORDS + tid];
    __syncthreads();
    float acc[NPOS];
#pragma unroll
    for (int f = 0; f < NPOS; ++f) acc[f] = 0.0f;
    for (int j = tid; j < N_NODES; j += 256) {
        int lj = lane[j];
        unsigned int pj = packed[j];
        unsigned int vj = pj >> 31;
        unsigned int bit = (unsigned int)(row[lj >> 6] >> (lj & 63)) & 1u;
        bool adj = (j == i) | (vi & vj & bit);
        float w = adj ? dinv[j] : 0.0f;
#pragma unroll
        for (int f = 0; f < NPOS; ++f)
            acc[f] += ((pj >> f) & 1u) ? w : 0.0f;
    }
    int l = tid & 63, wv = tid >> 6;
#pragma unroll
    for (int f = 0; f < NPOS; ++f) {
        float v = acc[f];
#pragma unroll
        for (int off = 32; off; off >>= 1) v += __shfl_down(v, off);
        if (l == 0) red[wv][f] = v;
    }
    __syncthreads();
    if (tid < NPOS) {
        float di = dinv[i];
        agg[i * NPOS + tid] = di * (red[0][tid] + red[1][tid] + red[2][tid] + red[3][tid]);
    }
}

// ---------------- K5: out[i][n] = bias[n] + sum_f agg[i][f] * W[n][f] ----------------
#define NT 512
#define IT 16
__global__ __launch_bounds__(256) void k5_out(const float* __restrict__ agg,
                                              const float* __restrict__ W,
                                              const float* __restrict__ bias,
                                              float* __restrict__ out) {
    __shared__ float Wt[NT * NPOS];
    __shared__ float bt[NT];
    __shared__ float at[IT * NPOS];
    int tid = threadIdx.x;
    int n0 = blockIdx.x * NT;
    int i0 = blockIdx.y * IT;
    for (int idx = tid; idx < NT * NPOS; idx += 256) Wt[idx] = W[n0 * NPOS + idx];
    for (int idx = tid; idx < NT; idx += 256) bt[idx] = bias[n0 + idx];
    for (int idx = tid; idx < IT * NPOS; idx += 256) at[idx] = agg[i0 * NPOS + idx];
    __syncthreads();

    int n4 = (tid & 127) << 2;      // 0..508
    int ib = (tid >> 7) * 8;        // 0 or 8

    float wr[NPOS][4];
#pragma unroll
    for (int f = 0; f < NPOS; ++f)
#pragma unroll
        for (int r = 0; r < 4; ++r)
            wr[f][r] = Wt[(n4 + r) * NPOS + f];
    float b0 = bt[n4], b1 = bt[n4 + 1], b2 = bt[n4 + 2], b3 = bt[n4 + 3];

#pragma unroll
    for (int q = 0; q < 8; ++q) {
        int il = ib + q;
        float a0 = b0, a1 = b1, a2 = b2, a3 = b3;
#pragma unroll
        for (int f = 0; f < NPOS; ++f) {
            float av = at[il * NPOS + f];
            a0 += av * wr[f][0];
            a1 += av * wr[f][1];
            a2 += av * wr[f][2];
            a3 += av * wr[f][3];
        }
        float4 o = make_float4(a0, a1, a2, a3);
        *(float4*)&out[(size_t)(i0 + il) * N_NODES + n0 + n4] = o;
    }
}

extern "C" void kernel_launch(void* const* d_in, const int* in_sizes, int n_in,
                              void* d_out, int out_size, void* d_ws, size_t ws_size,
                              hipStream_t stream) {
    const float* nf   = (const float*)d_in[0];   // node_feature [1,3072,13]
    const float* topo = (const float*)d_in[1];   // topo [1,1,4096,4096]
    const float* W    = (const float*)d_in[2];   // gcn_weight [3072,13]
    const float* bias = (const float*)d_in[3];   // gcn_bias [3072]
    float* out = (float*)d_out;

    // scratch layout in ws (~2.3 MB used)
    char* ws = (char*)d_ws;
    int*          lane   = (int*)ws;                               // 12 KB
    unsigned int* packed = (unsigned int*)(ws + 12288);            // 12 KB
    float*        dinv   = (float*)(ws + 24576);                   // 12 KB
    float*        agg    = (float*)(ws + 36864);                   // 160 KB
    unsigned long long* T = (unsigned long long*)(ws + 262144);    // 2 MB [4096][64]

    kA_mask_lanes<<<(LL / 64) * (LL / 64) + 1, 256, 0, stream>>>(topo, nf, T, lane, packed);
    k3_deg<<<N_NODES, 256, 0, stream>>>(T, lane, packed, dinv);
    k4_agg<<<N_NODES, 256, 0, stream>>>(T, lane, packed, dinv, agg);
    dim3 g5(N_NODES / NT, N_NODES / IT);
    k5_out<<<g5, 256, 0, stream>>>(agg, W, bias, out);
}

// Round 3
// 64.469 us; speedup vs baseline: 1.2825x; 1.0709x over previous
//
#include <hip/hip_runtime.h>
#include <stdint.h>

#define N_NODES 3072
#define NPOS 13
#define LL 4096
#define LWORDS 64   // uint64 words per 4096-bit mask row

// ---------------- K1: lane codes + packed bits + rowneed flags (one block) ----------------
__global__ __launch_bounds__(1024) void k1_lanes(const float* __restrict__ nf,
                                                 int* __restrict__ lane,
                                                 unsigned int* __restrict__ packed,
                                                 unsigned char* __restrict__ rowneed) {
    int tid = threadIdx.x;
    ((int*)rowneed)[tid] = 0;          // zero 4096 flag bytes (ws is poisoned, must init)
    __syncthreads();
    for (int i = tid; i < N_NODES; i += 1024) {
        const float* b = nf + i * NPOS;
        unsigned int p = 0;
        int ln = 0;
#pragma unroll
        for (int k = 0; k < NPOS; ++k) {
            int bit = (int)b[k];             // values are exactly 0.0 / 1.0
            if (bit) p |= (1u << k);
            if (k < NPOS - 1) ln = ln * 2 + bit;  // MSB-first, first 12 bits
        }
        bool valid = (b[0] >= 0.0f);
        if (valid) p |= 0x80000000u;
        int lv = valid ? ln : 0;
        lane[i] = lv;
        packed[i] = p;
        rowneed[lv] = 1;                 // benign races, all write 1
    }
}

// ---------------- KA: sign-mask + bit-transpose, skipping unneeded rows/cols ----------
// Tile (tA,tB) of topo. Only rows flagged in rowneed are fetched; T-row bits at
// unneeded positions are garbage but provably never read downstream.
//   T[c][w] bit k  =  (topo[64w+k][c] >= 0)   (c,64w+k restricted to needed lanes)
__global__ __launch_bounds__(256) void kA_mask(const float* __restrict__ topo,
                                               const unsigned char* __restrict__ rowneed,
                                               unsigned long long* __restrict__ T) {
    int bid = blockIdx.x;
    int tid = threadIdx.x;
    int tA = bid & 63;   // row tile
    int tB = bid >> 6;   // col tile
    __shared__ float tile[64 * 65];   // pad 65: conflict-free column reads
    __shared__ unsigned char rflag[64], cflag[64];

    if (tid < 16) {
        ((int*)rflag)[tid] = ((const int*)(rowneed + tA * 64))[tid];
        ((int*)cflag)[tid] = ((const int*)(rowneed + tB * 64))[tid];
    }
    __syncthreads();

    const float* src = topo + (size_t)(tA * 64) * LL + tB * 64;
#pragma unroll
    for (int p = 0; p < 4; ++p) {
        int q = p * 1024 + tid * 4;       // linear float index in 64x64 tile
        int r = q >> 6, c = q & 63;
        if (rflag[r]) {
            float4 v = *(const float4*)&src[(size_t)r * LL + c];
            float* d = &tile[r * 65 + c];
            d[0] = v.x; d[1] = v.y; d[2] = v.z; d[3] = v.w;
        }
    }
    __syncthreads();

    int w = tid >> 6, l = tid & 63;
#pragma unroll
    for (int cc = 0; cc < 16; ++cc) {
        int col = w * 16 + cc;            // wave-uniform
        if (!cflag[col]) continue;        // uniform branch: ballot safe
        unsigned long long m = __ballot(tile[l * 65 + col] >= 0.0f);
        if (l == 0) T[(size_t)(tB * 64 + col) * LWORDS + tA] = m;
    }
}

// ---------------- K3: column degree -> dinv[i] = 1/sqrt(deg) ----------------
__global__ __launch_bounds__(256) void k3_deg(const unsigned long long* __restrict__ T,
                                              const int* __restrict__ lane,
                                              const unsigned int* __restrict__ packed,
                                              float* __restrict__ dinv) {
    int i = blockIdx.x;
    __shared__ unsigned long long row[LWORDS];
    __shared__ int red[4];
    int tid = threadIdx.x;
    int li = lane[i];
    unsigned int vi = packed[i] >> 31;
    if (tid < LWORDS) row[tid] = T[(size_t)li * LWORDS + tid];
    __syncthreads();
    int cnt = 0;
    for (int j = tid; j < N_NODES; j += 256) {
        int lj = lane[j];
        unsigned int vj = packed[j] >> 31;
        unsigned int bit = (unsigned int)(row[lj >> 6] >> (lj & 63)) & 1u;
        cnt += (int)((j == i) | (vi & vj & bit));
    }
#pragma unroll
    for (int off = 32; off; off >>= 1) cnt += __shfl_down(cnt, off);
    if ((tid & 63) == 0) red[tid >> 6] = cnt;
    __syncthreads();
    if (tid == 0) {
        int d = red[0] + red[1] + red[2] + red[3];
        dinv[i] = (d > 0) ? (1.0f / sqrtf((float)d)) : 0.0f;
    }
}

// ---------------- K4: agg[i][f] = dinv[i] * sum_j adj[j,i]*dinv[j]*bit_f(j) ----------------
__global__ __launch_bounds__(256) void k4_agg(const unsigned long long* __restrict__ T,
                                              const int* __restrict__ lane,
                                              const unsigned int* __restrict__ packed,
                                              const float* __restrict__ dinv,
                                              float* __restrict__ agg) {
    int i = blockIdx.x;
    __shared__ unsigned long long row[LWORDS];
    __shared__ float red[4][NPOS];
    int tid = threadIdx.x;
    int li = lane[i];
    unsigned int vi = packed[i] >> 31;
    if (tid < LWORDS) row[tid] = T[(size_t)li * LWORDS + tid];
    __syncthreads();
    float acc[NPOS];
#pragma unroll
    for (int f = 0; f < NPOS; ++f) acc[f] = 0.0f;
    for (int j = tid; j < N_NODES; j += 256) {
        int lj = lane[j];
        unsigned int pj = packed[j];
        unsigned int vj = pj >> 31;
        unsigned int bit = (unsigned int)(row[lj >> 6] >> (lj & 63)) & 1u;
        bool adj = (j == i) | (vi & vj & bit);
        float w = adj ? dinv[j] : 0.0f;
#pragma unroll
        for (int f = 0; f < NPOS; ++f)
            acc[f] += ((pj >> f) & 1u) ? w : 0.0f;
    }
    int l = tid & 63, wv = tid >> 6;
#pragma unroll
    for (int f = 0; f < NPOS; ++f) {
        float v = acc[f];
#pragma unroll
        for (int off = 32; off; off >>= 1) v += __shfl_down(v, off);
        if (l == 0) red[wv][f] = v;
    }
    __syncthreads();
    if (tid < NPOS) {
        float di = dinv[i];
        agg[i * NPOS + tid] = di * (red[0][tid] + red[1][tid] + red[2][tid] + red[3][tid]);
    }
}

// ---------------- K5: out[i][n] = bias[n] + sum_f agg[i][f] * W[n][f] ----------------
#define NT 256
#define IT 32
__global__ __launch_bounds__(256) void k5_out(const float* __restrict__ agg,
                                              const float* __restrict__ W,
                                              const float* __restrict__ bias,
                                              float* __restrict__ out) {
    __shared__ float Wt[NT * NPOS];   // 13312 B
    __shared__ float bt[NT];
    __shared__ float at[IT * NPOS];
    int tid = threadIdx.x;
    int n0 = blockIdx.x * NT;
    int i0 = blockIdx.y * IT;
    // float4 staging (all bases 16B-aligned: NT*NPOS*4 = 13312, IT*NPOS*4 = 1664)
    const float4* Wsrc = (const float4*)&W[(size_t)n0 * NPOS];
    for (int idx = tid; idx < NT * NPOS / 4; idx += 256) ((float4*)Wt)[idx] = Wsrc[idx];
    if (tid < NT / 4) ((float4*)bt)[tid] = ((const float4*)&bias[n0])[tid];
    if (tid < IT * NPOS / 4) ((float4*)at)[tid] = ((const float4*)&agg[(size_t)i0 * NPOS])[tid];
    __syncthreads();

    int n4 = (tid & 63) << 2;        // col group: 0..252
    int r0 = (tid >> 6) << 3;        // row group: 0,8,16,24

    float wr[NPOS][4];
#pragma unroll
    for (int f = 0; f < NPOS; ++f)
#pragma unroll
        for (int r = 0; r < 4; ++r)
            wr[f][r] = Wt[(n4 + r) * NPOS + f];
    float b0 = bt[n4], b1 = bt[n4 + 1], b2 = bt[n4 + 2], b3 = bt[n4 + 3];

#pragma unroll
    for (int q = 0; q < 8; ++q) {
        int il = r0 + q;
        float a0 = b0, a1 = b1, a2 = b2, a3 = b3;
#pragma unroll
        for (int f = 0; f < NPOS; ++f) {
            float av = at[il * NPOS + f];
            a0 += av * wr[f][0];
            a1 += av * wr[f][1];
            a2 += av * wr[f][2];
            a3 += av * wr[f][3];
        }
        float4 o = make_float4(a0, a1, a2, a3);
        *(float4*)&out[(size_t)(i0 + il) * N_NODES + n0 + n4] = o;
    }
}

extern "C" void kernel_launch(void* const* d_in, const int* in_sizes, int n_in,
                              void* d_out, int out_size, void* d_ws, size_t ws_size,
                              hipStream_t stream) {
    const float* nf   = (const float*)d_in[0];   // node_feature [1,3072,13]
    const float* topo = (const float*)d_in[1];   // topo [1,1,4096,4096]
    const float* W    = (const float*)d_in[2];   // gcn_weight [3072,13]
    const float* bias = (const float*)d_in[3];   // gcn_bias [3072]
    float* out = (float*)d_out;

    // scratch layout in ws (~2.3 MB used)
    char* ws = (char*)d_ws;
    int*           lane    = (int*)ws;                              // 12 KB
    unsigned int*  packed  = (unsigned int*)(ws + 12288);           // 12 KB
    float*         dinv    = (float*)(ws + 24576);                  // 12 KB
    float*         agg     = (float*)(ws + 36864);                  // 160 KB
    unsigned char* rowneed = (unsigned char*)(ws + 200704);         // 4 KB
    unsigned long long* T  = (unsigned long long*)(ws + 262144);    // 2 MB [4096][64]

    k1_lanes<<<1, 1024, 0, stream>>>(nf, lane, packed, rowneed);
    kA_mask<<<(LL / 64) * (LL / 64), 256, 0, stream>>>(topo, rowneed, T);
    k3_deg<<<N_NODES, 256, 0, stream>>>(T, lane, packed, dinv);
    k4_agg<<<N_NODES, 256, 0, stream>>>(T, lane, packed, dinv, agg);
    dim3 g5(N_NODES / NT, N_NODES / IT);
    k5_out<<<g5, 256, 0, stream>>>(agg, W, bias, out);
}